// Round 7
// baseline (825.315 us; speedup 1.0000x reference)
//
#include <hip/hip_runtime.h>
#include <hip/hip_bf16.h>
#include <stdint.h>

#define BATCH 8
#define SEQ 2048
#define DMODEL 1024

typedef __attribute__((ext_vector_type(4))) float f32x4;
typedef __attribute__((ext_vector_type(8))) short bf16x8;
typedef __attribute__((ext_vector_type(4))) uint32_t u32x4;
typedef __attribute__((ext_vector_type(2))) uint32_t u32x2;

#define MFMA16(a, b, c) __builtin_amdgcn_mfma_f32_16x16x32_bf16((a), (b), (c), 0, 0, 0)

// ---------------------------------------------------------------------------
// PK ("panel-k-major") operand layout, used for ALL bf16 GEMM operands:
//   elem(r,k) at offset (r>>4)*(Kd*16) + (k>>3)*128 + (r&15)*8 + (k&7)
//  * BK=32 K-tile staging is 1KB-contiguous per wave instruction (coalesced),
//    lane-linear LDS dest (global_load_lds-legal);
//  * fragment ds_read_b128 is lane-linear (lane l reads byte l*16) -> zero
//    bank conflicts.
// ---------------------------------------------------------------------------

static __device__ __forceinline__ uint16_t f2bf(float f) {
    uint32_t u = __builtin_bit_cast(uint32_t, f);
    u += 0x7fffu + ((u >> 16) & 1u);   // round-to-nearest-even
    return (uint16_t)(u >> 16);
}
static __device__ __forceinline__ uint32_t pk2(float lo, float hi) {
    return (uint32_t)f2bf(lo) | ((uint32_t)f2bf(hi) << 16);
}
// async global->LDS, 16B per lane. LDS dest is wave-uniform base + lane*16.
static __device__ __forceinline__ void gload16(const uint16_t* g, uint16_t* l) {
    __builtin_amdgcn_global_load_lds((const __attribute__((address_space(1))) void*)g,
                                     (__attribute__((address_space(3))) void*)l, 16, 0, 0);
}

// ---------------------------------------------------------------------------
// Kernel 0: f32 row-major -> bf16 PK cast.
// ---------------------------------------------------------------------------
__global__ __launch_bounds__(256) void cast_bf16_pk(const float* __restrict__ src,
                                                    uint16_t* __restrict__ dst) {
    const size_t c = (size_t)blockIdx.x * 256 + threadIdx.x;  // PK chunk id
    const size_t panel = c >> 11;           // 2048 chunks per 16x1024 panel
    const int w = (int)(c & 2047);
    const int ks = w >> 4, r15 = w & 15;
    const float* s = src + (panel * 16 + r15) * DMODEL + ks * 8;
    f32x4 a = *(const f32x4*)s;
    f32x4 b = *(const f32x4*)(s + 4);
    u32x4 o = {pk2(a[0], a[1]), pk2(a[2], a[3]), pk2(b[0], b[1]), pk2(b[2], b[3])};
    *(u32x4*)(dst + c * 8) = o;
}

// ---------------------------------------------------------------------------
// Kernel 1: cast + transpose weights into PK.  WT_pk(n,k) = W[k][n].
// ---------------------------------------------------------------------------
__global__ void wt_cast_kernel(const float* __restrict__ Wk, const float* __restrict__ Wv,
                               const float* __restrict__ Wq, uint16_t* __restrict__ WT) {
    const float* W = blockIdx.z == 0 ? Wk : (blockIdx.z == 1 ? Wv : Wq);
    uint16_t* dst = WT + (size_t)blockIdx.z * DMODEL * DMODEL;
    __shared__ float tile[32][33];
    const int x = blockIdx.x * 32, y = blockIdx.y * 32;
    const int tx = threadIdx.x, ty = threadIdx.y;
#pragma unroll
    for (int j = 0; j < 4; j++)
        tile[ty * 4 + j][tx] = W[(size_t)(y + ty * 4 + j) * DMODEL + x + tx];
    __syncthreads();
#pragma unroll
    for (int j = 0; j < 4; j++) {
        const int n = x + ty * 4 + j, k = y + tx;
        const size_t off = ((size_t)(n >> 4) * (DMODEL / 8) + (k >> 3)) * 128 +
                           (n & 15) * 8 + (k & 7);
        dst[off] = f2bf(tile[tx][ty * 4 + j]);
    }
}

// ---------------------------------------------------------------------------
// Kernel 2: pipelined 256x(NB*64) B^T GEMM on PK operands.
//   C[b][m][n] = sum_k A[b][m][k] * Bt[b][n][k]
// 8 waves (2M x 4N), BK=32, 2-slot LDS double-buffer (64/48 KB -> 2-3
// blocks/CU for cross-block latency hiding), prefetch depth 1, counted
// vmcnt(L) (L = loads/STAGE; only the last tile drains to 0), raw s_barrier,
// setprio MFMA.  Staging coalesced 1KB/wave-instr; ds_reads lane-linear.
// NB=4: BN=256.  NB=2: BN=128.
// BX=1: batch on blockIdx.x -> XCD = batch.
// MODE 0: bf16 C in PK (Kd=ldc), * scale.   MODE 1: bf16 V-transpose into
// PK over [e][s] (Kd=SEQ).                  MODE 2: f32 plain C * Linv[row].
// ---------------------------------------------------------------------------
#define STAGE(tile, s)                                                       \
    do {                                                                     \
        const size_t ko_ = (size_t)(tile) * 512;                             \
        gload16(Ab + ko_ + abase0, &As[s][t * 8]);                           \
        gload16(Ab + ko_ + abase1, &As[s][t * 8 + 4096]);                    \
        gload16(Bb + ko_ + bbase0, &Bs[s][t * 8]);                           \
        if constexpr (NB == 4)                                               \
            gload16(Bb + ko_ + bbase1, &Bs[s][t * 8 + 4096]);                \
    } while (0)

#define KBODY(s, WAITSTR)                                                              \
    do {                                                                               \
        asm volatile("s_waitcnt " WAITSTR ::: "memory");                               \
        __builtin_amdgcn_s_barrier();                                                  \
        bf16x8 bfr[NB], afr[8];                                                        \
        _Pragma("unroll") for (int j = 0; j < NB; j++)                                 \
            bfr[j] = *(const bf16x8*)&Bs[s][(wc * NB + j) * 512 + lg * 128 + lr * 8];  \
        _Pragma("unroll") for (int i = 0; i < 8; i++)                                  \
            afr[i] = *(const bf16x8*)&As[s][(wr * 8 + i) * 512 + lg * 128 + lr * 8];   \
        __builtin_amdgcn_s_setprio(1);                                                 \
        _Pragma("unroll") for (int i = 0; i < 4; i++)                                  \
            _Pragma("unroll") for (int j = 0; j < NB; j++)                             \
                acc[i][j] = MFMA16(afr[i], bfr[j], acc[i][j]);                         \
        __builtin_amdgcn_s_setprio(0);                                                 \
        __builtin_amdgcn_s_setprio(1);                                                 \
        _Pragma("unroll") for (int i = 4; i < 8; i++)                                  \
            _Pragma("unroll") for (int j = 0; j < NB; j++)                             \
                acc[i][j] = MFMA16(afr[i], bfr[j], acc[i][j]);                         \
        __builtin_amdgcn_s_setprio(0);                                                 \
        asm volatile("s_waitcnt lgkmcnt(0)" ::: "memory");                             \
        __builtin_amdgcn_sched_barrier(0);                                             \
        __builtin_amdgcn_s_barrier();                                                  \
    } while (0)

template <int MODE, int BX, int NB>
__global__ __launch_bounds__(512, 2) void gemm256(const uint16_t* __restrict__ Ag,
                                                  const uint16_t* __restrict__ Bg,
                                                  void* __restrict__ Cg,
                                                  const float* __restrict__ Linv,
                                                  float scale, int lda, int ldb, int ldc,
                                                  int nk, size_t sA, size_t sB, size_t sC) {
    __shared__ __align__(16) uint16_t As[2][256 * 32];
    __shared__ __align__(16) uint16_t Bs[2][NB * 64 * 32];
    const int bz = BX ? blockIdx.x : blockIdx.z;
    const int bm = BX ? blockIdx.y : blockIdx.x;
    const int bn = BX ? blockIdx.z : blockIdx.y;
    const int m0 = bm * 256, n0 = bn * (NB * 64);
    const uint16_t* Ab = Ag + (size_t)bz * sA + (size_t)m0 * lda;
    const uint16_t* Bb = Bg + (size_t)bz * sB + (size_t)n0 * ldb;
    const int t = threadIdx.x, lane = t & 63;
    const int wid = t >> 6, wr = wid >> 2, wc = wid & 3;
    const int lr = lane & 15, lg = lane >> 4;
    // PK staging: chunk c: 16-row block c>>6, within-block chunk c&63.
    const size_t eldA = (size_t)lda * 16, eldB = (size_t)ldb * 16;
    const size_t abase0 = (size_t)(t >> 6) * eldA + (t & 63) * 8;
    const size_t abase1 = abase0 + 8 * eldA;
    const size_t bbase0 = (size_t)(t >> 6) * eldB + (t & 63) * 8;
    const size_t bbase1 = bbase0 + 8 * eldB;   // used only when NB==4

    f32x4 acc[8][NB] = {};
    STAGE(0, 0);
    int buf = 0;
    for (int kt = 0; kt < nk; ++kt) {
        if (kt + 1 < nk) {
            STAGE(kt + 1, buf ^ 1);
            if constexpr (NB == 4) { KBODY(buf, "vmcnt(4)"); }
            else                   { KBODY(buf, "vmcnt(3)"); }
        } else {
            KBODY(buf, "vmcnt(0)");
        }
        buf ^= 1;
    }

    if constexpr (MODE == 0) {
        uint16_t* C = (uint16_t*)Cg + (size_t)bz * sC;
#pragma unroll
        for (int i = 0; i < 8; i++) {
            const int gm = m0 + wr * 128 + i * 16 + lg * 4;   // gm&15 == lg*4
            const size_t pbase = (size_t)(gm >> 4) * (ldc / 8);
#pragma unroll
            for (int j = 0; j < NB; j++) {
                const int gn = n0 + wc * (NB * 16) + j * 16 + lr;
                const size_t off = (pbase + (gn >> 3)) * 128 + (gn & 7);
#pragma unroll
                for (int r = 0; r < 4; r++)
                    C[off + (lg * 4 + r) * 8] = f2bf(acc[i][j][r] * scale);
            }
        }
    } else if constexpr (MODE == 1) {
        uint16_t* C = (uint16_t*)Cg;
#pragma unroll
        for (int i = 0; i < 8; i++) {
            const int gm = m0 + wr * 128 + i * 16 + lg * 4;  // global m = b*SEQ + s
            const int bb = gm / SEQ;                         // uniform per block
            const int s0 = gm - bb * SEQ;                    // s0&7 in {0,4}
            uint16_t* Cb = C + (size_t)bb * DMODEL * SEQ;
#pragma unroll
            for (int j = 0; j < NB; j++) {
                const int e = n0 + wc * (NB * 16) + j * 16 + lr;
                const size_t off = ((size_t)(e >> 4) * (SEQ / 8) + (s0 >> 3)) * 128 +
                                   (e & 15) * 8 + (s0 & 7);
                u32x2 v = {pk2(acc[i][j][0], acc[i][j][1]), pk2(acc[i][j][2], acc[i][j][3])};
                *(u32x2*)&Cb[off] = v;
            }
        }
    } else {
        float* C = (float*)Cg + (size_t)bz * sC;
        const float* LB = Linv + bz * SEQ;
#pragma unroll
        for (int i = 0; i < 8; i++) {
            const int gm = m0 + wr * 128 + i * 16 + lg * 4;
            const f32x4 lv = *(const f32x4*)&LB[gm];
#pragma unroll
            for (int j = 0; j < NB; j++) {
                const int gn = n0 + wc * (NB * 16) + j * 16 + lr;
#pragma unroll
                for (int r = 0; r < 4; r++)
                    C[(size_t)(gm + r) * ldc + gn] = acc[i][j][r] * lv[r];
            }
        }
    }
}

// ---------------------------------------------------------------------------
// Kernel 3: row softmax on PK-layout S, in place.  One block per 16-row panel
// (contiguous 32KB).  Thread t owns row t&15, k-slots (t>>4)+16u, u=0..15.
// ---------------------------------------------------------------------------
__global__ __launch_bounds__(256) void softmax_pk(uint16_t* __restrict__ S,
                                                  float* __restrict__ Linv) {
    const size_t panel = blockIdx.x;
    uint16_t* sp = S + panel * (size_t)(16 * SEQ);
    const int t = threadIdx.x, lane = t & 63, w = t >> 6;
    const int r15 = t & 15, ksl = t >> 4;
    __shared__ float rm[4][16], rs[4][16];
    u32x4 raw[16];
    float mx = -3.0e38f;
#pragma unroll
    for (int u = 0; u < 16; u++) {
        raw[u] = *(const u32x4*)&sp[(ksl + u * 16) * 128 + r15 * 8];
#pragma unroll
        for (int j = 0; j < 4; j++) {
            mx = fmaxf(mx, __builtin_bit_cast(float, raw[u][j] << 16));
            mx = fmaxf(mx, __builtin_bit_cast(float, raw[u][j] & 0xffff0000u));
        }
    }
    mx = fmaxf(mx, __shfl_xor(mx, 16));
    mx = fmaxf(mx, __shfl_xor(mx, 32));
    if (lane < 16) rm[w][lane] = mx;
    __syncthreads();
    const float m = fmaxf(fmaxf(rm[0][r15], rm[1][r15]), fmaxf(rm[2][r15], rm[3][r15]));
    float sum = 0.0f;
#pragma unroll
    for (int u = 0; u < 16; u++) {
#pragma unroll
        for (int j = 0; j < 4; j++) {
            float lo = __expf(__builtin_bit_cast(float, raw[u][j] << 16) - m);
            float hi = __expf(__builtin_bit_cast(float, raw[u][j] & 0xffff0000u) - m);
            sum += lo + hi;
            raw[u][j] = pk2(lo, hi);
        }
    }
    sum += __shfl_xor(sum, 16);
    sum += __shfl_xor(sum, 32);
    if (lane < 16) rs[w][lane] = sum;
    __syncthreads();
    const float tot = rs[0][r15] + rs[1][r15] + rs[2][r15] + rs[3][r15];
#pragma unroll
    for (int u = 0; u < 16; u++)
        *(u32x4*)&sp[(ksl + u * 16) * 128 + r15 * 8] = raw[u];
    if (w == 0 && lane < 16) Linv[panel * 16 + lane] = 1.0f / tot;
}

// ---------------------------------------------------------------------------
// Workspace layout (bytes), all bf16 matrices in PK layout:
//   Qbf [16384][1024] :          0   (Q pre-scaled by 1/32)
//   Kbf [16384][1024] :  33,554,432
//   VTb [8][1024][2048]: 67,108,864
//   WT  [3][1024][1024]:100,663,296
//   Linv[16384] f32   : 106,954,752
//   S/P [8][2048][2048]:107,020,288  (P in place)
//   Xbf [16384][1024] :171,966,464  (reused for Xq, Xk, Xv in turn)
// ---------------------------------------------------------------------------
extern "C" void kernel_launch(void* const* d_in, const int* in_sizes, int n_in,
                              void* d_out, int out_size, void* d_ws, size_t ws_size,
                              hipStream_t stream) {
    const float* Xk = (const float*)d_in[0];
    const float* Xv = (const float*)d_in[1];
    const float* Xq = (const float*)d_in[2];
    const float* Wk = (const float*)d_in[3];
    const float* Wv = (const float*)d_in[4];
    const float* Wq = (const float*)d_in[5];
    float* out = (float*)d_out;
    char* ws = (char*)d_ws;
    uint16_t* Qbf = (uint16_t*)(ws);
    uint16_t* Kbf = (uint16_t*)(ws + (size_t)33554432);
    uint16_t* VTb = (uint16_t*)(ws + (size_t)67108864);
    uint16_t* WT  = (uint16_t*)(ws + (size_t)100663296);
    float*    Linv= (float*)(ws + (size_t)106954752);
    uint16_t* Sb  = (uint16_t*)(ws + (size_t)107020288);
    uint16_t* Xbf = (uint16_t*)(ws + (size_t)171966464);

    wt_cast_kernel<<<dim3(32, 32, 3), dim3(32, 8), 0, stream>>>(Wk, Wv, Wq, WT);
    // Q projection (scale 1/sqrt(1024) folded into bf16 store), 256x128 tile
    cast_bf16_pk<<<8192, 256, 0, stream>>>(Xq, Xbf);
    gemm256<0, 0, 2><<<dim3(64, 8, 1), 512, 0, stream>>>(
        Xbf, WT + 2 * 1048576, (void*)Qbf, nullptr, 0.03125f,
        DMODEL, DMODEL, DMODEL, DMODEL / 32, 0, 0, 0);
    // K projection
    cast_bf16_pk<<<8192, 256, 0, stream>>>(Xk, Xbf);
    gemm256<0, 0, 2><<<dim3(64, 8, 1), 512, 0, stream>>>(
        Xbf, WT, (void*)Kbf, nullptr, 1.0f,
        DMODEL, DMODEL, DMODEL, DMODEL / 32, 0, 0, 0);
    // V projection with transposed store -> VT PK over [e][s]
    cast_bf16_pk<<<8192, 256, 0, stream>>>(Xv, Xbf);
    gemm256<1, 0, 2><<<dim3(64, 8, 1), 512, 0, stream>>>(
        Xbf, WT + 1048576, (void*)VTb, nullptr, 1.0f,
        DMODEL, DMODEL, 0, DMODEL / 32, 0, 0, 0);
    // scores: S[b][q][k] = Qhat[b] . K[b]^T  (bf16 PK store), 256x256 tile
    gemm256<0, 1, 4><<<dim3(8, 8, 8), 512, 0, stream>>>(
        Qbf, Kbf, (void*)Sb, nullptr, 1.0f,
        DMODEL, DMODEL, SEQ, DMODEL / 32,
        (size_t)SEQ * DMODEL, (size_t)SEQ * DMODEL, (size_t)SEQ * SEQ);
    // in-place row softmax -> P, Linv
    softmax_pk<<<dim3(BATCH * SEQ / 16), 256, 0, stream>>>(Sb, Linv);
    // Z[b][q][e] = (P[b] . V[b]) * Linv  (f32 plain store), 256x128 tile
    gemm256<2, 1, 2><<<dim3(8, 8, 8), 512, 0, stream>>>(
        Sb, VTb, (void*)out, Linv, 1.0f,
        SEQ, SEQ, DMODEL, SEQ / 32,
        (size_t)SEQ * SEQ, (size_t)DMODEL * SEQ, (size_t)SEQ * DMODEL);
}

// Round 8
// 369.722 us; speedup vs baseline: 2.2323x; 2.2323x over previous
//
#include <hip/hip_runtime.h>
#include <hip/hip_bf16.h>
#include <stdint.h>

#define BATCH 8
#define SEQ 2048
#define DMODEL 1024

typedef __attribute__((ext_vector_type(4))) float f32x4;
typedef __attribute__((ext_vector_type(8))) short bf16x8;
typedef __attribute__((ext_vector_type(4))) uint32_t u32x4;
typedef __attribute__((ext_vector_type(2))) uint32_t u32x2;

#define MFMA16(a, b, c) __builtin_amdgcn_mfma_f32_16x16x32_bf16((a), (b), (c), 0, 0, 0)

// ---------------------------------------------------------------------------
// PK ("panel-k-major") operand layout for ALL bf16 GEMM operands:
//   elem(r,k) at offset (r>>4)*(Kd*16) + (k>>3)*128 + (r&15)*8 + (k&7)
//  * a 16-row block's 64-wide K-slice (one BK=64 tile) is 1024 elems (2 KB)
//    CONTIGUOUS in global -> staging is fully coalesced and lane-linear in
//    LDS (global_load_lds-legal);
//  * fragment ds_read_b128 is lane-linear (lane l reads byte l*16) -> zero
//    bank conflicts.
// ---------------------------------------------------------------------------

static __device__ __forceinline__ uint16_t f2bf(float f) {
    uint32_t u = __builtin_bit_cast(uint32_t, f);
    u += 0x7fffu + ((u >> 16) & 1u);   // round-to-nearest-even
    return (uint16_t)(u >> 16);
}
static __device__ __forceinline__ uint32_t pk2(float lo, float hi) {
    return (uint32_t)f2bf(lo) | ((uint32_t)f2bf(hi) << 16);
}
// async global->LDS, 16B per lane. LDS dest is wave-uniform base + lane*16.
static __device__ __forceinline__ void gload16(const uint16_t* g, uint16_t* l) {
    __builtin_amdgcn_global_load_lds((const __attribute__((address_space(1))) void*)g,
                                     (__attribute__((address_space(3))) void*)l, 16, 0, 0);
}

// ---------------------------------------------------------------------------
// Kernel 0: f32 row-major -> bf16 PK cast.
// ---------------------------------------------------------------------------
__global__ __launch_bounds__(256) void cast_bf16_pk(const float* __restrict__ src,
                                                    uint16_t* __restrict__ dst) {
    const size_t c = (size_t)blockIdx.x * 256 + threadIdx.x;  // PK chunk id
    const size_t panel = c >> 11;           // 2048 chunks per 16x1024 panel
    const int w = (int)(c & 2047);
    const int ks = w >> 4, r15 = w & 15;
    const float* s = src + (panel * 16 + r15) * DMODEL + ks * 8;
    f32x4 a = *(const f32x4*)s;
    f32x4 b = *(const f32x4*)(s + 4);
    u32x4 o = {pk2(a[0], a[1]), pk2(a[2], a[3]), pk2(b[0], b[1]), pk2(b[2], b[3])};
    *(u32x4*)(dst + c * 8) = o;
}

// ---------------------------------------------------------------------------
// Kernel 1: cast + transpose weights into PK.  WT_pk(n,k) = W[k][n].
// ---------------------------------------------------------------------------
__global__ void wt_cast_kernel(const float* __restrict__ Wk, const float* __restrict__ Wv,
                               const float* __restrict__ Wq, uint16_t* __restrict__ WT) {
    const float* W = blockIdx.z == 0 ? Wk : (blockIdx.z == 1 ? Wv : Wq);
    uint16_t* dst = WT + (size_t)blockIdx.z * DMODEL * DMODEL;
    __shared__ float tile[32][33];
    const int x = blockIdx.x * 32, y = blockIdx.y * 32;
    const int tx = threadIdx.x, ty = threadIdx.y;
#pragma unroll
    for (int j = 0; j < 4; j++)
        tile[ty * 4 + j][tx] = W[(size_t)(y + ty * 4 + j) * DMODEL + x + tx];
    __syncthreads();
#pragma unroll
    for (int j = 0; j < 4; j++) {
        const int n = x + ty * 4 + j, k = y + tx;
        const size_t off = ((size_t)(n >> 4) * (DMODEL / 8) + (k >> 3)) * 128 +
                           (n & 15) * 8 + (k & 7);
        dst[off] = f2bf(tile[tx][ty * 4 + j]);
    }
}

// ---------------------------------------------------------------------------
// Kernel 2: 8-phase pipelined 256x256 B^T GEMM (T3+T4+T5), BK=64, 8 waves
// (2M x 4N), double-buffered 128 KB LDS, PK operands.
//   C[b][m][n] = sum_k A[b][m][k] * Bt[b][n][k]
// Per phase: {4 ds_read_b128 (A quadrant) || stage one 16KB half (2
// global_load_lds) -> s_barrier -> lgkmcnt(0)+sched_barrier -> setprio(1),
// 16 MFMA, setprio(0) -> s_barrier}.  B-frags (8 reads) before ph1/ph5.
// Counted vmcnt(4) ONLY at phases 4 and 8 (2 halves stay in flight across
// iterations); never a full drain in the main loop.
// Stage-slot ledger (iteration computes tiles t=slot0, t+1=slot1):
//   ph1/2: A-halves of t+1 -> As[1]   (freed by prev ph8 end-barrier)
//   ph3/4: B-halves of t+2 -> Bs[0]   (freed by ph1: B_t read before ph1)
//   ph5/6: A-halves of t+2 -> As[0]   (freed by ph4: A_t read ph1-4)
//   ph7/8: B-halves of t+3 -> Bs[1]   (freed by ph5: B_{t+1} read at ph5)
// vmcnt(4)@ph4 => tile t+1 fully landed before ph5; @ph8 => t+2 before next.
// MODE 0: bf16 C in PK * scale. MODE 1: bf16 VT store (PK over [e][s]).
// MODE 2: f32 plain C * Linv[row].   BX=1: batch on blockIdx.x (XCD=batch).
// ---------------------------------------------------------------------------
#define STG_A(kt, sl, h)                                                          \
    do {                                                                          \
        const size_t g0 = (size_t)((h) * 8 + (tid >> 7)) * eldA +                 \
                          (size_t)(kt) * 1024 + (tid & 127) * 8;                  \
        gload16(Ab + g0, &As[sl][(h) * 8192 + tid * 8]);                          \
        gload16(Ab + g0 + 4 * eldA, &As[sl][(h) * 8192 + tid * 8 + 4096]);        \
    } while (0)
#define STG_B(kt, sl, h)                                                          \
    do {                                                                          \
        const size_t g0 = (size_t)((h) * 8 + (tid >> 7)) * eldB +                 \
                          (size_t)(kt) * 1024 + (tid & 127) * 8;                  \
        gload16(Bb + g0, &Bs[sl][(h) * 8192 + tid * 8]);                          \
        gload16(Bb + g0 + 4 * eldB, &Bs[sl][(h) * 8192 + tid * 8 + 4096]);        \
    } while (0)

#define READ_B(sl)                                                                \
    _Pragma("unroll") for (int j = 0; j < 4; j++) {                               \
        bfr[j][0] = *(const bf16x8*)&Bs[sl][(wc * 4 + j) * 1024 + lbase];         \
        bfr[j][1] = *(const bf16x8*)&Bs[sl][(wc * 4 + j) * 1024 + 512 + lbase];   \
    }

#define VM4 asm volatile("s_waitcnt vmcnt(4)" ::: "memory")
#define VM0 asm volatile("s_waitcnt vmcnt(0)" ::: "memory")
#define NOPW (void)0
#define NOST (void)0

#define PH(sl, q, STG, WAIT)                                                      \
    do {                                                                          \
        const int ab = (wr * 8 + 2 * (q)) * 1024 + lbase;                         \
        bf16x8 a00 = *(const bf16x8*)&As[sl][ab];                                 \
        bf16x8 a01 = *(const bf16x8*)&As[sl][ab + 512];                           \
        bf16x8 a10 = *(const bf16x8*)&As[sl][ab + 1024];                          \
        bf16x8 a11 = *(const bf16x8*)&As[sl][ab + 1536];                          \
        STG;                                                                      \
        WAIT;                                                                     \
        __builtin_amdgcn_s_barrier();                                             \
        asm volatile("s_waitcnt lgkmcnt(0)" ::: "memory");                        \
        __builtin_amdgcn_sched_barrier(0);                                        \
        __builtin_amdgcn_s_setprio(1);                                            \
        _Pragma("unroll") for (int j = 0; j < 4; j++) {                           \
            acc[2 * (q)][j] = MFMA16(a00, bfr[j][0], acc[2 * (q)][j]);            \
            acc[2 * (q)][j] = MFMA16(a01, bfr[j][1], acc[2 * (q)][j]);            \
            acc[2 * (q) + 1][j] = MFMA16(a10, bfr[j][0], acc[2 * (q) + 1][j]);    \
            acc[2 * (q) + 1][j] = MFMA16(a11, bfr[j][1], acc[2 * (q) + 1][j]);    \
        }                                                                         \
        __builtin_amdgcn_s_setprio(0);                                            \
        __builtin_amdgcn_s_barrier();                                             \
    } while (0)

template <int MODE, int BX>
__global__ __launch_bounds__(512, 2) void gemm8p(const uint16_t* __restrict__ Ag,
                                                 const uint16_t* __restrict__ Bg,
                                                 void* __restrict__ Cg,
                                                 const float* __restrict__ Linv,
                                                 float scale, int lda, int ldb, int ldc,
                                                 int nk, size_t sA, size_t sB, size_t sC) {
    __shared__ __align__(16) uint16_t As[2][16384];   // 64 KB
    __shared__ __align__(16) uint16_t Bs[2][16384];   // 64 KB
    const int bz = BX ? blockIdx.x : blockIdx.z;
    const int bm = BX ? blockIdx.y : blockIdx.x;
    const int bn = BX ? blockIdx.z : blockIdx.y;
    const int m0 = bm * 256, n0 = bn * 256;
    const uint16_t* Ab = Ag + (size_t)bz * sA + (size_t)m0 * lda;  // PK panel base
    const uint16_t* Bb = Bg + (size_t)bz * sB + (size_t)n0 * ldb;
    const int tid = threadIdx.x, lane = tid & 63;
    const int wid = tid >> 6, wr = wid >> 2, wc = wid & 3;
    const int lr = lane & 15, lg = lane >> 4;
    const int lbase = lg * 128 + lr * 8;
    const size_t eldA = (size_t)lda * 16, eldB = (size_t)ldb * 16;

    f32x4 acc[8][4] = {};
    bf16x8 bfr[4][2];
    // prologue: tile0 (A0,A1,B0,B1) + tile1 (B0,B1); vmcnt(4) keeps tile1's
    // B-halves in flight, tile0 landed.
    STG_A(0, 0, 0); STG_A(0, 0, 1);
    STG_B(0, 0, 0); STG_B(0, 0, 1);
    STG_B(1, 1, 0); STG_B(1, 1, 1);
    VM4;
    __builtin_amdgcn_s_barrier();
    for (int kt = 0; kt + 3 < nk; kt += 2) {
        READ_B(0);
        PH(0, 0, STG_A(kt + 1, 1, 0), NOPW);
        PH(0, 1, STG_A(kt + 1, 1, 1), NOPW);
        PH(0, 2, STG_B(kt + 2, 0, 0), NOPW);
        PH(0, 3, STG_B(kt + 2, 0, 1), VM4);
        READ_B(1);
        PH(1, 0, STG_A(kt + 2, 0, 0), NOPW);
        PH(1, 1, STG_A(kt + 2, 0, 1), NOPW);
        PH(1, 2, STG_B(kt + 3, 1, 0), NOPW);
        PH(1, 3, STG_B(kt + 3, 1, 1), VM4);
    }
    // epilogue iteration: tiles nk-2, nk-1 (no staging beyond nk-1)
    READ_B(0);
    PH(0, 0, STG_A(nk - 1, 1, 0), NOPW);
    PH(0, 1, STG_A(nk - 1, 1, 1), NOPW);
    PH(0, 2, NOST, NOPW);
    PH(0, 3, NOST, VM0);
    READ_B(1);
    PH(1, 0, NOST, NOPW);
    PH(1, 1, NOST, NOPW);
    PH(1, 2, NOST, NOPW);
    PH(1, 3, NOST, NOPW);

    if constexpr (MODE == 0) {
        uint16_t* C = (uint16_t*)Cg + (size_t)bz * sC;
#pragma unroll
        for (int i = 0; i < 8; i++) {
            const int gm = m0 + wr * 128 + i * 16 + lg * 4;   // gm&15 == lg*4
            const size_t pbase = (size_t)(gm >> 4) * (ldc / 8);
#pragma unroll
            for (int j = 0; j < 4; j++) {
                const int gn = n0 + wc * 64 + j * 16 + lr;
                const size_t off = (pbase + (gn >> 3)) * 128 + (gn & 7);
#pragma unroll
                for (int r = 0; r < 4; r++)
                    C[off + (lg * 4 + r) * 8] = f2bf(acc[i][j][r] * scale);
            }
        }
    } else if constexpr (MODE == 1) {
        uint16_t* C = (uint16_t*)Cg;
#pragma unroll
        for (int i = 0; i < 8; i++) {
            const int gm = m0 + wr * 128 + i * 16 + lg * 4;  // global m = b*SEQ + s
            const int bb = gm / SEQ;                         // uniform per block
            const int s0 = gm - bb * SEQ;                    // s0&7 in {0,4}
            uint16_t* Cb = C + (size_t)bb * DMODEL * SEQ;
#pragma unroll
            for (int j = 0; j < 4; j++) {
                const int e = n0 + wc * 64 + j * 16 + lr;
                const size_t off = ((size_t)(e >> 4) * (SEQ / 8) + (s0 >> 3)) * 128 +
                                   (e & 15) * 8 + (s0 & 7);
                u32x2 v = {pk2(acc[i][j][0], acc[i][j][1]), pk2(acc[i][j][2], acc[i][j][3])};
                *(u32x2*)&Cb[off] = v;
            }
        }
    } else {
        float* C = (float*)Cg + (size_t)bz * sC;
        const float* LB = Linv + bz * SEQ;
#pragma unroll
        for (int i = 0; i < 8; i++) {
            const int gm = m0 + wr * 128 + i * 16 + lg * 4;
            const f32x4 lv = *(const f32x4*)&LB[gm];
#pragma unroll
            for (int j = 0; j < 4; j++) {
                const int gn = n0 + wc * 64 + j * 16 + lr;
#pragma unroll
                for (int r = 0; r < 4; r++)
                    C[(size_t)(gm + r) * ldc + gn] = acc[i][j][r] * lv[r];
            }
        }
    }
}

// ---------------------------------------------------------------------------
// Kernel 3: row softmax on PK-layout S, in place.  One block per 16-row panel
// (contiguous 32KB).  Thread t owns row t&15, k-slots (t>>4)+16u, u=0..15.
// ---------------------------------------------------------------------------
__global__ __launch_bounds__(256) void softmax_pk(uint16_t* __restrict__ S,
                                                  float* __restrict__ Linv) {
    const size_t panel = blockIdx.x;
    uint16_t* sp = S + panel * (size_t)(16 * SEQ);
    const int t = threadIdx.x, lane = t & 63, w = t >> 6;
    const int r15 = t & 15, ksl = t >> 4;
    __shared__ float rm[4][16], rs[4][16];
    u32x4 raw[16];
    float mx = -3.0e38f;
#pragma unroll
    for (int u = 0; u < 16; u++) {
        raw[u] = *(const u32x4*)&sp[(ksl + u * 16) * 128 + r15 * 8];
#pragma unroll
        for (int j = 0; j < 4; j++) {
            mx = fmaxf(mx, __builtin_bit_cast(float, raw[u][j] << 16));
            mx = fmaxf(mx, __builtin_bit_cast(float, raw[u][j] & 0xffff0000u));
        }
    }
    mx = fmaxf(mx, __shfl_xor(mx, 16));
    mx = fmaxf(mx, __shfl_xor(mx, 32));
    if (lane < 16) rm[w][lane] = mx;
    __syncthreads();
    const float m = fmaxf(fmaxf(rm[0][r15], rm[1][r15]), fmaxf(rm[2][r15], rm[3][r15]));
    float sum = 0.0f;
#pragma unroll
    for (int u = 0; u < 16; u++) {
#pragma unroll
        for (int j = 0; j < 4; j++) {
            float lo = __expf(__builtin_bit_cast(float, raw[u][j] << 16) - m);
            float hi = __expf(__builtin_bit_cast(float, raw[u][j] & 0xffff0000u) - m);
            sum += lo + hi;
            raw[u][j] = pk2(lo, hi);
        }
    }
    sum += __shfl_xor(sum, 16);
    sum += __shfl_xor(sum, 32);
    if (lane < 16) rs[w][lane] = sum;
    __syncthreads();
    const float tot = rs[0][r15] + rs[1][r15] + rs[2][r15] + rs[3][r15];
#pragma unroll
    for (int u = 0; u < 16; u++)
        *(u32x4*)&sp[(ksl + u * 16) * 128 + r15 * 8] = raw[u];
    if (w == 0 && lane < 16) Linv[panel * 16 + lane] = 1.0f / tot;
}

// ---------------------------------------------------------------------------
// Workspace layout (bytes), all bf16 matrices in PK layout:
//   Qbf [16384][1024] :          0   (Q pre-scaled by 1/32)
//   Kbf [16384][1024] :  33,554,432
//   VTb [8][1024][2048]: 67,108,864
//   WT  [3][1024][1024]:100,663,296
//   Linv[16384] f32   : 106,954,752
//   S/P [8][2048][2048]:107,020,288  (P in place)
//   Xbf [16384][1024] :171,966,464  (reused for Xq, Xk, Xv in turn)
// ---------------------------------------------------------------------------
extern "C" void kernel_launch(void* const* d_in, const int* in_sizes, int n_in,
                              void* d_out, int out_size, void* d_ws, size_t ws_size,
                              hipStream_t stream) {
    const float* Xk = (const float*)d_in[0];
    const float* Xv = (const float*)d_in[1];
    const float* Xq = (const float*)d_in[2];
    const float* Wk = (const float*)d_in[3];
    const float* Wv = (const float*)d_in[4];
    const float* Wq = (const float*)d_in[5];
    float* out = (float*)d_out;
    char* ws = (char*)d_ws;
    uint16_t* Qbf = (uint16_t*)(ws);
    uint16_t* Kbf = (uint16_t*)(ws + (size_t)33554432);
    uint16_t* VTb = (uint16_t*)(ws + (size_t)67108864);
    uint16_t* WT  = (uint16_t*)(ws + (size_t)100663296);
    float*    Linv= (float*)(ws + (size_t)106954752);
    uint16_t* Sb  = (uint16_t*)(ws + (size_t)107020288);
    uint16_t* Xbf = (uint16_t*)(ws + (size_t)171966464);

    wt_cast_kernel<<<dim3(32, 32, 3), dim3(32, 8), 0, stream>>>(Wk, Wv, Wq, WT);
    // Q projection (scale 1/sqrt(1024) folded into bf16 store)
    cast_bf16_pk<<<8192, 256, 0, stream>>>(Xq, Xbf);
    gemm8p<0, 0><<<dim3(64, 4, 1), 512, 0, stream>>>(
        Xbf, WT + 2 * 1048576, (void*)Qbf, nullptr, 0.03125f,
        DMODEL, DMODEL, DMODEL, DMODEL / 64, 0, 0, 0);
    // K projection
    cast_bf16_pk<<<8192, 256, 0, stream>>>(Xk, Xbf);
    gemm8p<0, 0><<<dim3(64, 4, 1), 512, 0, stream>>>(
        Xbf, WT, (void*)Kbf, nullptr, 1.0f,
        DMODEL, DMODEL, DMODEL, DMODEL / 64, 0, 0, 0);
    // V projection with transposed store -> VT PK over [e][s]
    cast_bf16_pk<<<8192, 256, 0, stream>>>(Xv, Xbf);
    gemm8p<1, 0><<<dim3(64, 4, 1), 512, 0, stream>>>(
        Xbf, WT + 1048576, (void*)VTb, nullptr, 1.0f,
        DMODEL, DMODEL, 0, DMODEL / 64, 0, 0, 0);
    // scores: S[b][q][k] = Qhat[b] . K[b]^T  (bf16 PK store)
    gemm8p<0, 1><<<dim3(8, 8, 8), 512, 0, stream>>>(
        Qbf, Kbf, (void*)Sb, nullptr, 1.0f,
        DMODEL, DMODEL, SEQ, DMODEL / 64,
        (size_t)SEQ * DMODEL, (size_t)SEQ * DMODEL, (size_t)SEQ * SEQ);
    // in-place row softmax -> P, Linv
    softmax_pk<<<dim3(BATCH * SEQ / 16), 256, 0, stream>>>(Sb, Linv);
    // Z[b][q][e] = (P[b] . V[b]) * Linv  (f32 plain store)
    gemm8p<2, 1><<<dim3(8, 8, 4), 512, 0, stream>>>(
        Sb, VTb, (void*)out, Linv, 1.0f,
        SEQ, SEQ, DMODEL, SEQ / 64,
        (size_t)SEQ * SEQ, (size_t)DMODEL * SEQ, (size_t)SEQ * DMODEL);
}